// Round 12
// baseline (1533.714 us; speedup 1.0000x reference)
//
#include <hip/hip_runtime.h>

typedef _Float16 f16x8 __attribute__((ext_vector_type(8)));
typedef float    f32x4 __attribute__((ext_vector_type(4)));
typedef unsigned u32x4 __attribute__((ext_vector_type(4)));

#define DEV __device__ __forceinline__

DEV float fexp2(float x){ return __builtin_amdgcn_exp2f(x); }
DEV float frcp (float x){ return __builtin_amdgcn_rcpf(x); }

// Pre-scaled sigmoid (arg already * -log2e) -- used only by LSTM1.
DEV float sgm(float p){ return frcp(1.0f + fexp2(p)); }
// tanh(c), natural-domain c -- trans path (LSTM1 c1, LSTM2 c2 chains).
DEV float tnc(float c){ return fmaf(2.f, sgm(c * -2.88539008177792682f), -1.f); }

// cross-lane via __shfl_xor ONLY (validated R8)
DEV float shx(float v, int m){ return __shfl_xor(v, m, 64); }

// RNE f16 pack
DEV unsigned pkrne(float a, float b){
  unsigned short ha = __builtin_bit_cast(unsigned short, (_Float16)a);
  unsigned short hb = __builtin_bit_cast(unsigned short, (_Float16)b);
  return (unsigned)ha | ((unsigned)hb << 16);
}

#define L2E_N  (-1.44269504088896341f)
#define L2E2_N (-2.88539008177792682f)

// Table sigmoid: t = x*32 + 512 (x in [-16,16)); piecewise-linear, err <= 1.2e-5.
// One ds_read_b64 + ~7 VALU; offloads the saturated trans pipe (R10: ~85% of
// busy cycles were v_exp/v_rcp).
DEV float tsig(const float2* tb, float t){
  const float tc = __builtin_fminf(__builtin_fmaxf(t, 0.0f), 1023.0f);
  const int   i  = (int)tc;
  const float fr = tc - (float)i;
  const float2 e = tb[i];
  return fmaf(e.y, fr, e.x);
}

// 16 seqs/wave. Lane l: n=l&15 (seq col / A-row), g=l>>4 (k-group).
// Shared A/B labeling k=4g+e, slots e<4 only (validated R7/R8); e>=4 zero.
// Software-pipelined: d_pre = mfma(A_hh2,B_h2prev,bias) issued previous iter.
// LSTM2/LSTM3 weights NATURAL domain (table handles scaling via index consts:
// sigma -> *32, tanh -> *64). LSTM1 stays pre-scaled on the trans pipe
// (latency-critical h1 recurrence; DS ~120cy latency would stretch it).
__global__ __launch_bounds__(256, 1)
void lstm3_kernel(const float* __restrict__ x,
                  const float* __restrict__ w_ih1, const float* __restrict__ w_hh1,
                  const float* __restrict__ b_ih1, const float* __restrict__ b_hh1,
                  const float* __restrict__ w_ih2, const float* __restrict__ w_hh2,
                  const float* __restrict__ b_ih2, const float* __restrict__ b_hh2,
                  const float* __restrict__ w_ih3, const float* __restrict__ w_hh3,
                  const float* __restrict__ b_ih3, const float* __restrict__ b_hh3,
                  const float* __restrict__ w_lin, const float* __restrict__ b_lin,
                  float* __restrict__ out, int T)
{
  __shared__ float2 stb[1024];

  const int tid = threadIdx.x;

  // ---- build sigma table (exact trans sigma at 1025 nodes; (y, dy) pairs) ----
  for (int i = tid; i < 1024; i += 256){
    const float xv = (float)(i - 512) * 0.03125f;
    const float y0 = frcp(1.0f + fexp2(xv * L2E_N));
    const float y1 = frcp(1.0f + fexp2((xv + 0.03125f) * L2E_N));
    stb[i] = make_float2(y0, y1 - y0);
  }
  __syncthreads();

  const int l   = tid & 63;
  const int n   = l & 15;
  const int g   = l >> 4;
  const int wv  = tid >> 6;
  const int seq = 16 * (blockIdx.x * 4 + wv) + n;

  // ---------------- LSTM1 (pre-scaled, trans path): rows g and 4+g ----------------
  const int rA = g, rB = 4 + g;
  const float sAq = L2E_N;
  const float sBq = (g < 2) ? L2E2_N : L2E_N;       // rows 4,5 = g-gate
  const float m1  = (g < 2) ? 2.0f : 1.0f;
  const float a1  = (g < 2) ? -1.0f : 0.0f;
  const float w1ax = w_ih1[2*rA]*sAq,  w1ay = w_ih1[2*rA+1]*sAq;
  const float w1ah0 = w_hh1[2*rA]*sAq, w1ah1 = w_hh1[2*rA+1]*sAq;
  const float bbA  = (b_ih1[rA] + b_hh1[rA]) * sAq;
  const float w1bx = w_ih1[2*rB]*sBq,  w1by = w_ih1[2*rB+1]*sBq;
  const float w1bh0 = w_hh1[2*rB]*sBq, w1bh1 = w_hh1[2*rB+1]*sBq;
  const float bbB  = (b_ih1[rB] + b_hh1[rB]) * sBq;

  // ---------------- LSTM2: A fragments (NATURAL domain) ----------------
  f16x8 af[4];   // w_hh2, slots e<4 = k 4g+e
  f16x8 a2f[4];  // w_ih2, g0 slots e0/e1
  f32x4 cb[4];
  #pragma unroll
  for (int t = 0; t < 4; ++t){
    #pragma unroll
    for (int e = 0; e < 8; ++e){
      float v = 0.0f;
      if (e < 4) v = w_hh2[(16*t + n)*16 + (4*g + e)];
      af[t][e] = (_Float16)v;
      float v2 = 0.0f;
      if (g == 0 && e < 2) v2 = w_ih2[(16*t + n)*2 + e];
      a2f[t][e] = (_Float16)v2;
    }
    #pragma unroll
    for (int j = 0; j < 4; ++j){
      const int r = 16*t + 4*g + j;
      cb[t][j] = b_ih2[r] + b_hh2[r];
    }
  }

  // ---------------- LSTM3 lane-local (NATURAL domain): A row n = gate (n&3) ----------------
  f16x8 a3f;
  #pragma unroll
  for (int e = 0; e < 8; ++e){
    float v = 0.0f;
    if (e < 4) v = w_ih3[16*(n & 3) + 4*g + e];
    a3f[e] = (_Float16)v;
  }
  f32x4 c3v;
  c3v[0] = b_ih3[0] + b_hh3[0];
  c3v[1] = b_ih3[1] + b_hh3[1];
  c3v[2] = b_ih3[2] + b_hh3[2];
  c3v[3] = b_ih3[3] + b_hh3[3];
  const float wh30 = w_hh3[0], wh31 = w_hh3[1], wh32 = w_hh3[2], wh33 = w_hh3[3];
  const float wl = w_lin[0], bl = b_lin[0];

  // ---------------- state ----------------
  float c1 = 0.f, c3 = 0.f;
  float c2[4] = {0.f, 0.f, 0.f, 0.f};
  float h1a_all = 0.f, h1b_all = 0.f, h3 = 0.f;
  unsigned pAu = 0u, pBu = 0u;

  const float* xrow = x + (size_t)seq * (size_t)(2*T);
  float*       orow = out + (size_t)seq * (size_t)T;

  float4 pa = *(const float4*)(xrow);
  float4 pb = *(const float4*)(xrow + 4);

  float o0 = 0.f, o1 = 0.f, o2 = 0.f, o3 = 0.f;

  // prologue: d_pre for step 0 (h2_prev = 0 -> d_pre = bias)
  f32x4 dp0, dp1, dp2, dp3;
  {
    u32x4 bu; bu[0] = 0u; bu[1] = 0u; bu[2] = 0u; bu[3] = 0u;
    const f16x8 bv = __builtin_bit_cast(f16x8, bu);
    dp0 = __builtin_amdgcn_mfma_f32_16x16x32_f16(af[0], bv, cb[0], 0, 0, 0);
    dp1 = __builtin_amdgcn_mfma_f32_16x16x32_f16(af[1], bv, cb[1], 0, 0, 0);
    dp2 = __builtin_amdgcn_mfma_f32_16x16x32_f16(af[2], bv, cb[2], 0, 0, 0);
    dp3 = __builtin_amdgcn_mfma_f32_16x16x32_f16(af[3], bv, cb[3], 0, 0, 0);
  }

  const int NCH = T / 4;
  for (int ch = 0; ch < NCH; ++ch){
    const float4 ca = pa, cbv = pb;
    const int no = (ch + 1 < NCH) ? (ch + 1) * 8 : 0;
    pa = *(const float4*)(xrow + no);
    pb = *(const float4*)(xrow + no + 4);

    const bool cap = (g == (ch & 3));

    #pragma unroll
    for (int s = 0; s < 4; ++s){
      const float x0 = (s==0)?ca.x:(s==1)?ca.z:(s==2)?cbv.x:cbv.z;
      const float x1 = (s==0)?ca.y:(s==1)?ca.w:(s==2)?cbv.y:cbv.w;

      // ---------- LSTM1 (trans path, latency-critical) ----------
      const float gA = fmaf(w1ax, x0, fmaf(w1ay, x1,
                       fmaf(w1ah0, h1a_all, fmaf(w1ah1, h1b_all, bbA))));
      const float gB = fmaf(w1bx, x0, fmaf(w1by, x1,
                       fmaf(w1bh0, h1a_all, fmaf(w1bh1, h1b_all, bbB))));
      const float zA = sgm(gA);                     // r0:i0 r1:i1 r2:f0 r3:f1
      const float zB = fmaf(sgm(gB), m1, a1);       // r0:g0 r1:g1 r2:o0 r3:o1
      const float ig1 = zA * zB;
      const float fm = shx(zA, 32);
      c1 = fmaf(fm, c1, ig1);
      const float th1 = tnc(c1);
      const float om = shx(zB, 32);
      const float h1v = om * th1;                   // r0: h1a, r1: h1b
      const float t16 = shx(h1v, 16);
      const unsigned h1p = pkrne(h1v, t16);         // g0 lanes: (h1a,h1b)
      u32x4 b2u; b2u[0] = (g == 0) ? h1p : 0u; b2u[1] = 0u; b2u[2] = 0u; b2u[3] = 0u;
      const f16x8 b2v = __builtin_bit_cast(f16x8, b2u);
      const float a_c = (g & 1) ? t16 : h1v;
      const float b_c = (g & 1) ? h1v : t16;
      const float a32 = shx(a_c, 32);
      const float b32 = shx(b_c, 32);
      h1a_all = (g & 2) ? a32 : a_c;
      h1b_all = (g & 2) ? b32 : b_c;

      // ---------- h1-injection MFMA (chains onto carried d_pre) ----------
      const f32x4 d0 = __builtin_amdgcn_mfma_f32_16x16x32_f16(a2f[0], b2v, dp0, 0, 0, 0);
      const f32x4 d1 = __builtin_amdgcn_mfma_f32_16x16x32_f16(a2f[1], b2v, dp1, 0, 0, 0);
      const f32x4 d2 = __builtin_amdgcn_mfma_f32_16x16x32_f16(a2f[2], b2v, dp2, 0, 0, 0);
      const f32x4 d3 = __builtin_amdgcn_mfma_f32_16x16x32_f16(a2f[3], b2v, dp3, 0, 0, 0);

      // ---------- LSTM2 activations + cell (gates via LDS table) ----------
      float h2l[4];
      #pragma unroll
      for (int j = 0; j < 4; ++j){
        const float ii = tsig(stb, fmaf(d0[j], 32.f, 512.f));
        const float ff = tsig(stb, fmaf(d1[j], 32.f, 512.f));
        const float gg = fmaf(2.f, tsig(stb, fmaf(d2[j], 64.f, 512.f)), -1.f);
        const float oo = tsig(stb, fmaf(d3[j], 32.f, 512.f));
        c2[j] = fmaf(ff, c2[j], ii * gg);
        h2l[j] = oo * tnc(c2[j]);                   // tanh(c2) stays trans (chain latency)
      }
      pAu = pkrne(h2l[0], h2l[1]);
      pBu = pkrne(h2l[2], h2l[3]);

      // ---------- issue NEXT step's h2-recurrence MFMA now ----------
      u32x4 bu; bu[0] = pAu; bu[1] = pBu; bu[2] = 0u; bu[3] = 0u;
      const f16x8 bv = __builtin_bit_cast(f16x8, bu);
      dp0 = __builtin_amdgcn_mfma_f32_16x16x32_f16(af[0], bv, cb[0], 0, 0, 0);
      dp1 = __builtin_amdgcn_mfma_f32_16x16x32_f16(af[1], bv, cb[1], 0, 0, 0);
      dp2 = __builtin_amdgcn_mfma_f32_16x16x32_f16(af[2], bv, cb[2], 0, 0, 0);
      dp3 = __builtin_amdgcn_mfma_f32_16x16x32_f16(af[3], bv, cb[3], 0, 0, 0);

      // ---------- LSTM3: lane-local, all activations via table ----------
      const f32x4 d3v = __builtin_amdgcn_mfma_f32_16x16x32_f16(a3f, bv, c3v, 0, 0, 0);
      const float p_i = fmaf(wh30, h3, d3v[0]);
      const float p_f = fmaf(wh31, h3, d3v[1]);
      const float p_g = fmaf(wh32, h3, d3v[2]);
      const float p_o = fmaf(wh33, h3, d3v[3]);
      const float i3 = tsig(stb, fmaf(p_i, 32.f, 512.f));
      const float f3 = tsig(stb, fmaf(p_f, 32.f, 512.f));
      const float g3 = fmaf(2.f, tsig(stb, fmaf(p_g, 64.f, 512.f)), -1.f);
      const float q3 = tsig(stb, fmaf(p_o, 32.f, 512.f));
      c3 = fmaf(f3, c3, i3 * g3);
      const float th3 = fmaf(2.f, tsig(stb, fmaf(c3, 64.f, 512.f)), -1.f);
      h3 = q3 * th3;
      const float yv = fmaf(wl, h3, bl);

      if      (s == 0) o0 = cap ? yv : o0;
      else if (s == 1) o1 = cap ? yv : o1;
      else if (s == 2) o2 = cap ? yv : o2;
      else             o3 = cap ? yv : o3;
    }

    if ((ch & 3) == 3){
      float4 o4; o4.x = o0; o4.y = o1; o4.z = o2; o4.w = o3;
      *(float4*)(orow + (ch >> 2) * 16 + 4 * g) = o4;
    }
  }
}

extern "C" void kernel_launch(void* const* d_in, const int* in_sizes, int n_in,
                              void* d_out, int out_size, void* d_ws, size_t ws_size,
                              hipStream_t stream)
{
  const float* x     = (const float*)d_in[0];
  const float* w_ih1 = (const float*)d_in[1];
  const float* w_hh1 = (const float*)d_in[2];
  const float* b_ih1 = (const float*)d_in[3];
  const float* b_hh1 = (const float*)d_in[4];
  const float* w_ih2 = (const float*)d_in[5];
  const float* w_hh2 = (const float*)d_in[6];
  const float* b_ih2 = (const float*)d_in[7];
  const float* b_hh2 = (const float*)d_in[8];
  const float* w_ih3 = (const float*)d_in[9];
  const float* w_hh3 = (const float*)d_in[10];
  const float* b_ih3 = (const float*)d_in[11];
  const float* b_hh3 = (const float*)d_in[12];
  const float* w_lin = (const float*)d_in[13];
  const float* b_lin = (const float*)d_in[14];
  float* out = (float*)d_out;

  const int T = 2048;
  const int B = in_sizes[0] / (2 * T);     // 16384
  const int waves   = B / 16;              // 1024
  const int blocks  = waves / 4;           // 256

  lstm3_kernel<<<blocks, 256, 0, stream>>>(
      x, w_ih1, w_hh1, b_ih1, b_hh1,
      w_ih2, w_hh2, b_ih2, b_hh2,
      w_ih3, w_hh3, b_ih3, b_hh3,
      w_lin, b_lin, out, T);
}

// Round 13
// 1379.672 us; speedup vs baseline: 1.1117x; 1.1117x over previous
//
#include <hip/hip_runtime.h>

typedef _Float16 f16x8 __attribute__((ext_vector_type(8)));
typedef float    f32x4 __attribute__((ext_vector_type(4)));
typedef unsigned u32x4 __attribute__((ext_vector_type(4)));

#define DEV __device__ __forceinline__

DEV float fexp2(float x){ return __builtin_amdgcn_exp2f(x); }
DEV float frcp (float x){ return __builtin_amdgcn_rcpf(x); }

// Pre-scaled sigmoid: arg already multiplied by -log2e (folded into weights).
DEV float sgm(float p){ return frcp(1.0f + fexp2(p)); }
// tanh(c), natural-domain c (one mul, then pre-scaled sigmoid).
DEV float tnc(float c){ return fmaf(2.f, sgm(c * -2.88539008177792682f), -1.f); }

DEV float shx(float v, int m){ return __shfl_xor(v, m, 64); }
DEV unsigned shxu(unsigned v, int m){ return (unsigned)__shfl_xor((int)v, m, 64); }

// RNE f16 pack
DEV unsigned pkrne(float a, float b){
  unsigned short ha = __builtin_bit_cast(unsigned short, (_Float16)a);
  unsigned short hb = __builtin_bit_cast(unsigned short, (_Float16)b);
  return (unsigned)ha | ((unsigned)hb << 16);
}

#define L2E_N  (-1.44269504088896341f)
#define L2E2_N (-2.88539008177792682f)

// 8 seqs/wave, 2048 waves -> 2 waves/SIMD (R10 was 1 wave/SIMD, ~380cy/step idle).
// Lane l: n=l&7 (seq), b8=(l>>3)&1, gp=l>>4, col=l&15, kk=2*gp+b8 (LSTM1 row).
// MIRRORED COLUMNS: B cols n and n+8 both carry seq n's h2 (lane n+8 gets the
// partner half-pack via 1 shuffle) -> all D cols valid -> LSTM2's 16 units
// spread over all 64 lanes by SELECTS (b8 ? d[2,3] : d[0,1]), and LSTM3 is
// lane-local everywhere. Shared A/B k-labeling k=4*gp+e (validated R7-R10).
// Software pipeline: d_pre = mfma(A_hh2, B_h2prev, bias) issued previous step.
__global__ __launch_bounds__(256, 2)
void lstm3_kernel(const float* __restrict__ x,
                  const float* __restrict__ w_ih1, const float* __restrict__ w_hh1,
                  const float* __restrict__ b_ih1, const float* __restrict__ b_hh1,
                  const float* __restrict__ w_ih2, const float* __restrict__ w_hh2,
                  const float* __restrict__ b_ih2, const float* __restrict__ b_hh2,
                  const float* __restrict__ w_ih3, const float* __restrict__ w_hh3,
                  const float* __restrict__ b_ih3, const float* __restrict__ b_hh3,
                  const float* __restrict__ w_lin, const float* __restrict__ b_lin,
                  float* __restrict__ out, int T)
{
  const int tid = threadIdx.x;
  const int l   = tid & 63;
  const int n   = l & 7;
  const int b8  = (l >> 3) & 1;
  const int gp  = l >> 4;
  const int col = l & 15;
  const int kk  = (gp << 1) | b8;      // 0..7: LSTM1 gate row / capture phase
  const int wv  = tid >> 6;
  const int seq = 8 * (blockIdx.x * 4 + wv) + n;

  // ---------------- LSTM1: 1 gate row per lane (row kk of i0,i1,f0,f1,g0,g1,o0,o1) ----------------
  const float sc1 = (kk == 4 || kk == 5) ? L2E2_N : L2E_N;
  const float m1  = (kk == 4 || kk == 5) ? 2.0f : 1.0f;
  const float a1v = (kk == 4 || kk == 5) ? -1.0f : 0.0f;
  const float w1x0 = w_ih1[2*kk]   * sc1;
  const float w1x1 = w_ih1[2*kk+1] * sc1;
  const float w1h0 = w_hh1[2*kk]   * sc1;
  const float w1h1 = w_hh1[2*kk+1] * sc1;
  const float bb1  = (b_ih1[kk] + b_hh1[kk]) * sc1;

  // ---------------- LSTM2: A fragments (pre-scaled) ----------------
  f16x8 af[4];          // w_hh2, slots e<4 = k 4gp+e, A row = col
  unsigned a2p[4];      // w_ih2 pair for slots e0,e1 (gp==0 lanes only)
  f32x4 cb[4];
  #pragma unroll
  for (int t = 0; t < 4; ++t){
    const float sc = (t == 2) ? L2E2_N : L2E_N;
    #pragma unroll
    for (int e = 0; e < 8; ++e){
      float v = 0.0f;
      if (e < 4) v = w_hh2[(16*t + col)*16 + (4*gp + e)];
      af[t][e] = (_Float16)(v * sc);
    }
    if (gp == 0)
      a2p[t] = pkrne(w_ih2[(16*t + col)*2 + 0] * sc,
                     w_ih2[(16*t + col)*2 + 1] * sc);
    else
      a2p[t] = 0u;
    #pragma unroll
    for (int j = 0; j < 4; ++j){
      const int r = 16*t + 4*gp + j;
      cb[t][j] = (b_ih2[r] + b_hh2[r]) * sc;
    }
  }

  // ---------------- LSTM3: A row = col -> gate (col&3); lane-local gates ----------------
  const float s3n = ((col & 3) == 2) ? L2E2_N : L2E_N;
  f16x8 a3f;
  #pragma unroll
  for (int e = 0; e < 8; ++e){
    float v = 0.0f;
    if (e < 4) v = w_ih3[16*(col & 3) + 4*gp + e] * s3n;
    a3f[e] = (_Float16)v;
  }
  f32x4 c3v;
  c3v[0] = (b_ih3[0] + b_hh3[0]) * L2E_N;
  c3v[1] = (b_ih3[1] + b_hh3[1]) * L2E_N;
  c3v[2] = (b_ih3[2] + b_hh3[2]) * L2E2_N;
  c3v[3] = (b_ih3[3] + b_hh3[3]) * L2E_N;
  const float wh30 = w_hh3[0] * L2E_N,  wh31 = w_hh3[1] * L2E_N;
  const float wh32 = w_hh3[2] * L2E2_N, wh33 = w_hh3[3] * L2E_N;
  const float wl = w_lin[0], bl = b_lin[0];

  // ---------------- state ----------------
  float c1 = 0.f, c3 = 0.f;
  float c2a = 0.f, c2b = 0.f;              // own 2 units: 4gp+2*b8 (+1)
  float h1a_all = 0.f, h1b_all = 0.f, h3 = 0.f;
  unsigned pAu = 0u, pBu = 0u;

  const float* xrow = x + (size_t)seq * (size_t)(2*T);
  float*       orow = out + (size_t)seq * (size_t)T;

  float4 pa = *(const float4*)(xrow);
  float4 pb = *(const float4*)(xrow + 4);

  float o0 = 0.f, o1 = 0.f, o2 = 0.f, o3 = 0.f;

  // prologue: d_pre for step 0 (h2_prev = 0 -> d_pre = bias)
  f32x4 dp0, dp1, dp2, dp3;
  {
    u32x4 bu; bu[0] = 0u; bu[1] = 0u; bu[2] = 0u; bu[3] = 0u;
    const f16x8 bv = __builtin_bit_cast(f16x8, bu);
    dp0 = __builtin_amdgcn_mfma_f32_16x16x32_f16(af[0], bv, cb[0], 0, 0, 0);
    dp1 = __builtin_amdgcn_mfma_f32_16x16x32_f16(af[1], bv, cb[1], 0, 0, 0);
    dp2 = __builtin_amdgcn_mfma_f32_16x16x32_f16(af[2], bv, cb[2], 0, 0, 0);
    dp3 = __builtin_amdgcn_mfma_f32_16x16x32_f16(af[3], bv, cb[3], 0, 0, 0);
  }

  const int NCH = T / 4;
  for (int ch = 0; ch < NCH; ++ch){
    const float4 ca = pa, cbv = pb;
    const int no = (ch + 1 < NCH) ? (ch + 1) * 8 : 0;
    pa = *(const float4*)(xrow + no);
    pb = *(const float4*)(xrow + no + 4);

    const bool cap = (kk == (ch & 7));

    #pragma unroll
    for (int s = 0; s < 4; ++s){
      const float x0 = (s==0)?ca.x:(s==1)?ca.z:(s==2)?cbv.x:cbv.z;
      const float x1 = (s==0)?ca.y:(s==1)?ca.w:(s==2)?cbv.y:cbv.w;

      // ---------- LSTM1 (R2 8-lane scheme; masks 8/16/32) ----------
      const float g1 = fmaf(w1x0, x0, fmaf(w1x1, x1,
                       fmaf(w1h0, h1a_all, fmaf(w1h1, h1b_all, bb1))));
      const float z1 = fmaf(sgm(g1), m1, a1v);      // kk: i0,i1,f0,f1,g0,g1,o0,o1
      const float t1 = shx(z1, 32);                 // kk0<-g0, kk2<-o0, ...
      const float ig1 = z1 * t1;                    // kk0,1: i*g
      const float u1 = shx(z1, 16);                 // kk0<-f0, kk1<-f1 (gp pair)
      const float v1 = shx(t1, 16);                 // kk0<-o0, kk1<-o1
      const float fv = (gp & 2) ? v1 : u1;
      const float ov = (gp & 2) ? u1 : v1;
      c1 = fmaf(fv, c1, ig1);                       // kk0: c1a, kk1: c1b
      const float th1 = tnc(c1);
      const float hh = ov * th1;                    // kk0: h1a (lane n), kk1: h1b (lane n+8)
      const float t8 = shx(hh, 8);
      const float ha0 = b8 ? t8 : hh;               // gp0 pair: h1a
      const float hb0 = b8 ? hh : t8;
      const float ua = shx(ha0, 16);
      const float ub = shx(hb0, 16);
      const float ha1 = (gp & 1) ? ua : ha0;
      const float hb1 = (gp & 1) ? ub : hb0;
      const float wa = shx(ha1, 32);
      const float wb = shx(hb1, 32);
      h1a_all = (gp & 2) ? wa : ha1;
      h1b_all = (gp & 2) ? wb : hb1;
      const unsigned h1p = pkrne(h1a_all, h1b_all);

      // ---------- h1-injection MFMA (chains onto carried d_pre) ----------
      u32x4 b2u; b2u[0] = (gp == 0) ? h1p : 0u; b2u[1] = 0u; b2u[2] = 0u; b2u[3] = 0u;
      const f16x8 b2v = __builtin_bit_cast(f16x8, b2u);
      u32x4 a2u0; a2u0[0] = a2p[0]; a2u0[1] = 0u; a2u0[2] = 0u; a2u0[3] = 0u;
      u32x4 a2u1; a2u1[0] = a2p[1]; a2u1[1] = 0u; a2u1[2] = 0u; a2u1[3] = 0u;
      u32x4 a2u2; a2u2[0] = a2p[2]; a2u2[1] = 0u; a2u2[2] = 0u; a2u2[3] = 0u;
      u32x4 a2u3; a2u3[0] = a2p[3]; a2u3[1] = 0u; a2u3[2] = 0u; a2u3[3] = 0u;
      const f32x4 d0 = __builtin_amdgcn_mfma_f32_16x16x32_f16(__builtin_bit_cast(f16x8, a2u0), b2v, dp0, 0, 0, 0);
      const f32x4 d1 = __builtin_amdgcn_mfma_f32_16x16x32_f16(__builtin_bit_cast(f16x8, a2u1), b2v, dp1, 0, 0, 0);
      const f32x4 d2 = __builtin_amdgcn_mfma_f32_16x16x32_f16(__builtin_bit_cast(f16x8, a2u2), b2v, dp2, 0, 0, 0);
      const f32x4 d3 = __builtin_amdgcn_mfma_f32_16x16x32_f16(__builtin_bit_cast(f16x8, a2u3), b2v, dp3, 0, 0, 0);

      // ---------- LSTM2 acts: own 2 units via selects (mirrored cols) ----------
      const float pAi = b8 ? d0[2] : d0[0], pBi = b8 ? d0[3] : d0[1];
      const float pAf = b8 ? d1[2] : d1[0], pBf = b8 ? d1[3] : d1[1];
      const float pAg = b8 ? d2[2] : d2[0], pBg = b8 ? d2[3] : d2[1];
      const float pAo = b8 ? d3[2] : d3[0], pBo = b8 ? d3[3] : d3[1];
      const float iA = sgm(pAi), fA = sgm(pAf), oA = sgm(pAo);
      const float gA2 = fmaf(2.f, sgm(pAg), -1.f);
      c2a = fmaf(fA, c2a, iA * gA2);
      const float h2a = oA * tnc(c2a);
      const float iB = sgm(pBi), fB = sgm(pBf), oB = sgm(pBo);
      const float gB2 = fmaf(2.f, sgm(pBg), -1.f);
      c2b = fmaf(fB, c2b, iB * gB2);
      const float h2b = oB * tnc(c2b);
      const unsigned pk  = pkrne(h2a, h2b);         // own pair (4gp+2b8, +1)
      const unsigned pko = shxu(pk, 8);             // partner pair
      pAu = b8 ? pko : pk;                          // slots e0,e1 = units 4gp+0,1
      pBu = b8 ? pk : pko;                          // slots e2,e3 = units 4gp+2,3

      // ---------- issue NEXT step's h2-recurrence MFMA ----------
      u32x4 bu; bu[0] = pAu; bu[1] = pBu; bu[2] = 0u; bu[3] = 0u;
      const f16x8 bv = __builtin_bit_cast(f16x8, bu);
      dp0 = __builtin_amdgcn_mfma_f32_16x16x32_f16(af[0], bv, cb[0], 0, 0, 0);
      dp1 = __builtin_amdgcn_mfma_f32_16x16x32_f16(af[1], bv, cb[1], 0, 0, 0);
      dp2 = __builtin_amdgcn_mfma_f32_16x16x32_f16(af[2], bv, cb[2], 0, 0, 0);
      dp3 = __builtin_amdgcn_mfma_f32_16x16x32_f16(af[3], bv, cb[3], 0, 0, 0);

      // ---------- LSTM3: lane-local on every lane (cols mirrored) ----------
      const f32x4 d3v = __builtin_amdgcn_mfma_f32_16x16x32_f16(a3f, bv, c3v, 0, 0, 0);
      const float p_i = fmaf(wh30, h3, d3v[0]);
      const float p_f = fmaf(wh31, h3, d3v[1]);
      const float p_g = fmaf(wh32, h3, d3v[2]);
      const float p_o = fmaf(wh33, h3, d3v[3]);
      const float i3 = sgm(p_i);
      const float f3 = sgm(p_f);
      const float g3 = fmaf(2.f, sgm(p_g), -1.f);
      const float q3 = sgm(p_o);
      c3 = fmaf(f3, c3, i3 * g3);
      h3 = q3 * tnc(c3);
      const float yv = fmaf(wl, h3, bl);

      if      (s == 0) o0 = cap ? yv : o0;
      else if (s == 1) o1 = cap ? yv : o1;
      else if (s == 2) o2 = cap ? yv : o2;
      else             o3 = cap ? yv : o3;
    }

    // every 32 steps: each of the seq's 8 lanes writes its captured float4
    // -> 32 consecutive floats per seq = 2 full 64B lines, written once.
    if ((ch & 7) == 7){
      float4 o4; o4.x = o0; o4.y = o1; o4.z = o2; o4.w = o3;
      *(float4*)(orow + (ch >> 3) * 32 + 4 * kk) = o4;
    }
  }
}

extern "C" void kernel_launch(void* const* d_in, const int* in_sizes, int n_in,
                              void* d_out, int out_size, void* d_ws, size_t ws_size,
                              hipStream_t stream)
{
  const float* x     = (const float*)d_in[0];
  const float* w_ih1 = (const float*)d_in[1];
  const float* w_hh1 = (const float*)d_in[2];
  const float* b_ih1 = (const float*)d_in[3];
  const float* b_hh1 = (const float*)d_in[4];
  const float* w_ih2 = (const float*)d_in[5];
  const float* w_hh2 = (const float*)d_in[6];
  const float* b_ih2 = (const float*)d_in[7];
  const float* b_hh2 = (const float*)d_in[8];
  const float* w_ih3 = (const float*)d_in[9];
  const float* w_hh3 = (const float*)d_in[10];
  const float* b_ih3 = (const float*)d_in[11];
  const float* b_hh3 = (const float*)d_in[12];
  const float* w_lin = (const float*)d_in[13];
  const float* b_lin = (const float*)d_in[14];
  float* out = (float*)d_out;

  const int T = 2048;
  const int B = in_sizes[0] / (2 * T);     // 16384
  const int waves   = B / 8;               // 2048 -> 2 waves/SIMD
  const int blocks  = waves / 4;           // 512 blocks of 256 threads

  lstm3_kernel<<<blocks, 256, 0, stream>>>(
      x, w_ih1, w_hh1, b_ih1, b_hh1,
      w_ih2, w_hh2, b_ih2, b_hh2,
      w_ih3, w_hh3, b_ih3, b_hh3,
      w_lin, b_lin, out, T);
}

// Round 14
// 1085.252 us; speedup vs baseline: 1.4132x; 1.2713x over previous
//
#include <hip/hip_runtime.h>

typedef _Float16 f16x8 __attribute__((ext_vector_type(8)));
typedef float    f32x4 __attribute__((ext_vector_type(4)));
typedef unsigned u32x4 __attribute__((ext_vector_type(4)));

#define DEV __device__ __forceinline__

DEV float fexp2(float x){ return __builtin_amdgcn_exp2f(x); }
DEV float frcp (float x){ return __builtin_amdgcn_rcpf(x); }

// Pre-scaled sigmoid: arg already multiplied by -log2e (folded into weights).
DEV float sgm(float p){ return frcp(1.0f + fexp2(p)); }
// tanh(c), natural-domain c.
DEV float tnc(float c){ return fmaf(2.f, sgm(c * -2.88539008177792682f), -1.f); }

DEV float shx(float v, int m){ return __shfl_xor(v, m, 64); }

// RNE f16 pack
DEV unsigned pkrne(float a, float b){
  unsigned short ha = __builtin_bit_cast(unsigned short, (_Float16)a);
  unsigned short hb = __builtin_bit_cast(unsigned short, (_Float16)b);
  return (unsigned)ha | ((unsigned)hb << 16);
}

#define L2E_N  (-1.44269504088896341f)
#define L2E2_N (-2.88539008177792682f)

// R10 structure (16 seqs/wave -- the per-seq-efficient layout; R13's 8-seq
// 2-wave variant regressed) + cross-step software pipelining: LSTM1 for step
// t+1 is computed during step t (it depends only on x(t+1), h1(t)), so its
// ~200cy serial chain interleaves with LSTM2/LSTM3 instead of preceding them.
// x loaded per-step as float2, prefetched 2 steps ahead (kills 8 selects/step).
// Lane l: n=l&15 (seq col / A-row), g=l>>4 (k-group). Shared A/B k-labeling
// k=4g+e, slots e<4 only (validated R7-R10); e>=4 zero both sides.
__global__ __launch_bounds__(256, 1)
void lstm3_kernel(const float* __restrict__ x,
                  const float* __restrict__ w_ih1, const float* __restrict__ w_hh1,
                  const float* __restrict__ b_ih1, const float* __restrict__ b_hh1,
                  const float* __restrict__ w_ih2, const float* __restrict__ w_hh2,
                  const float* __restrict__ b_ih2, const float* __restrict__ b_hh2,
                  const float* __restrict__ w_ih3, const float* __restrict__ w_hh3,
                  const float* __restrict__ b_ih3, const float* __restrict__ b_hh3,
                  const float* __restrict__ w_lin, const float* __restrict__ b_lin,
                  float* __restrict__ out, int T)
{
  const int tid = threadIdx.x;
  const int l   = tid & 63;
  const int n   = l & 15;
  const int g   = l >> 4;
  const int wv  = tid >> 6;
  const int seq = 16 * (blockIdx.x * 4 + wv) + n;

  // ---------------- LSTM1 (pre-scaled): rows g (i/f) and 4+g (g-gate/o) ----------------
  const int rA = g, rB = 4 + g;
  const float sAq = L2E_N;
  const float sBq = (g < 2) ? L2E2_N : L2E_N;
  const float m1  = (g < 2) ? 2.0f : 1.0f;
  const float a1  = (g < 2) ? -1.0f : 0.0f;
  const float w1ax = w_ih1[2*rA]*sAq,  w1ay = w_ih1[2*rA+1]*sAq;
  const float w1ah0 = w_hh1[2*rA]*sAq, w1ah1 = w_hh1[2*rA+1]*sAq;
  const float bbA  = (b_ih1[rA] + b_hh1[rA]) * sAq;
  const float w1bx = w_ih1[2*rB]*sBq,  w1by = w_ih1[2*rB+1]*sBq;
  const float w1bh0 = w_hh1[2*rB]*sBq, w1bh1 = w_hh1[2*rB+1]*sBq;
  const float bbB  = (b_ih1[rB] + b_hh1[rB]) * sBq;

  // ---------------- LSTM2: A fragments (pre-scaled) ----------------
  f16x8 af[4];   // w_hh2, slots e<4 = k 4g+e
  f16x8 a2f[4];  // w_ih2, g0 slots e0/e1
  f32x4 cb[4];
  #pragma unroll
  for (int t = 0; t < 4; ++t){
    const float sc = (t == 2) ? L2E2_N : L2E_N;
    #pragma unroll
    for (int e = 0; e < 8; ++e){
      float v = 0.0f;
      if (e < 4) v = w_hh2[(16*t + n)*16 + (4*g + e)];
      af[t][e] = (_Float16)(v * sc);
      float v2 = 0.0f;
      if (g == 0 && e < 2) v2 = w_ih2[(16*t + n)*2 + e];
      a2f[t][e] = (_Float16)(v2 * sc);
    }
    #pragma unroll
    for (int j = 0; j < 4; ++j){
      const int r = 16*t + 4*g + j;
      cb[t][j] = (b_ih2[r] + b_hh2[r]) * sc;
    }
  }

  // ---------------- LSTM3 lane-local (pre-scaled): A row n = gate (n&3) ----------------
  const float s3n = ((n & 3) == 2) ? L2E2_N : L2E_N;
  f16x8 a3f;
  #pragma unroll
  for (int e = 0; e < 8; ++e){
    float v = 0.0f;
    if (e < 4) v = w_ih3[16*(n & 3) + 4*g + e] * s3n;
    a3f[e] = (_Float16)v;
  }
  f32x4 c3v;
  c3v[0] = (b_ih3[0] + b_hh3[0]) * L2E_N;
  c3v[1] = (b_ih3[1] + b_hh3[1]) * L2E_N;
  c3v[2] = (b_ih3[2] + b_hh3[2]) * L2E2_N;
  c3v[3] = (b_ih3[3] + b_hh3[3]) * L2E_N;
  const float wh30 = w_hh3[0] * L2E_N,  wh31 = w_hh3[1] * L2E_N;
  const float wh32 = w_hh3[2] * L2E2_N, wh33 = w_hh3[3] * L2E_N;
  const float wl = w_lin[0], bl = b_lin[0];

  // ---------------- state ----------------
  float c1 = 0.f, c3 = 0.f;
  float c2[4] = {0.f, 0.f, 0.f, 0.f};
  float h1a_all = 0.f, h1b_all = 0.f, h3 = 0.f;
  unsigned pAu = 0u, pBu = 0u;
  unsigned h1p = 0u;                       // packed h1(t) for injection

  const float* xrow = x + (size_t)seq * (size_t)(2*T);
  float*       orow = out + (size_t)seq * (size_t)T;

  // x pipeline: x_pre holds x(t+1) at iteration t (prefetched 1-2 steps ahead)
  float2 x_use = *(const float2*)(xrow);       // x(0)
  float2 x_pre = *(const float2*)(xrow + 2);   // x(1)

  // ---- prologue: h1(0) from x(0), h1(-1)=0 ----
  #define LSTM1_STEP(X0, X1)                                                   \
  {                                                                            \
    const float gA = fmaf(w1ax, (X0), fmaf(w1ay, (X1),                         \
                     fmaf(w1ah0, h1a_all, fmaf(w1ah1, h1b_all, bbA))));        \
    const float gB = fmaf(w1bx, (X0), fmaf(w1by, (X1),                         \
                     fmaf(w1bh0, h1a_all, fmaf(w1bh1, h1b_all, bbB))));        \
    const float zA = sgm(gA);                                                  \
    const float zB = fmaf(sgm(gB), m1, a1);                                    \
    const float ig1 = zA * zB;                                                 \
    const float fm = shx(zA, 32);                                              \
    c1 = fmaf(fm, c1, ig1);                                                    \
    const float th1 = tnc(c1);                                                 \
    const float om = shx(zB, 32);                                              \
    const float h1v = om * th1;                                                \
    const float t16 = shx(h1v, 16);                                            \
    h1p = pkrne(h1v, t16);   /* meaningful on g0 lanes */                      \
    const float a_c = (g & 1) ? t16 : h1v;                                     \
    const float b_c = (g & 1) ? h1v : t16;                                     \
    const float a32 = shx(a_c, 32);                                            \
    const float b32 = shx(b_c, 32);                                            \
    h1a_all = (g & 2) ? a32 : a_c;                                             \
    h1b_all = (g & 2) ? b32 : b_c;                                             \
  }

  LSTM1_STEP(x_use.x, x_use.y)

  float o0 = 0.f, o1 = 0.f, o2 = 0.f, o3 = 0.f;

  // prologue: d_pre for step 0 (h2_prev = 0 -> d_pre = bias)
  f32x4 dp0, dp1, dp2, dp3;
  {
    u32x4 bu; bu[0] = 0u; bu[1] = 0u; bu[2] = 0u; bu[3] = 0u;
    const f16x8 bv = __builtin_bit_cast(f16x8, bu);
    dp0 = __builtin_amdgcn_mfma_f32_16x16x32_f16(af[0], bv, cb[0], 0, 0, 0);
    dp1 = __builtin_amdgcn_mfma_f32_16x16x32_f16(af[1], bv, cb[1], 0, 0, 0);
    dp2 = __builtin_amdgcn_mfma_f32_16x16x32_f16(af[2], bv, cb[2], 0, 0, 0);
    dp3 = __builtin_amdgcn_mfma_f32_16x16x32_f16(af[3], bv, cb[3], 0, 0, 0);
  }

  const int NCH = T / 4;
  for (int ch = 0; ch < NCH; ++ch){
    const bool cap = (g == (ch & 3));

    #pragma unroll
    for (int s = 0; s < 4; ++s){
      // ---------- inject h1(t) (chains onto carried d_pre) ----------
      u32x4 b2u; b2u[0] = (g == 0) ? h1p : 0u; b2u[1] = 0u; b2u[2] = 0u; b2u[3] = 0u;
      const f16x8 b2v = __builtin_bit_cast(f16x8, b2u);
      const f32x4 d0 = __builtin_amdgcn_mfma_f32_16x16x32_f16(a2f[0], b2v, dp0, 0, 0, 0);
      const f32x4 d1 = __builtin_amdgcn_mfma_f32_16x16x32_f16(a2f[1], b2v, dp1, 0, 0, 0);
      const f32x4 d2 = __builtin_amdgcn_mfma_f32_16x16x32_f16(a2f[2], b2v, dp2, 0, 0, 0);
      const f32x4 d3 = __builtin_amdgcn_mfma_f32_16x16x32_f16(a2f[3], b2v, dp3, 0, 0, 0);

      // ---------- x advance + prefetch x(t+2) ----------
      const float2 xv = x_pre;
      const int ti = 4*ch + s + 2;
      const int tc = (ti < T) ? ti : (T - 1);
      x_pre = *(const float2*)(xrow + 2*tc);

      // ---------- LSTM1 for step t+1 (independent of d; interleaves) ----------
      LSTM1_STEP(xv.x, xv.y)

      // ---------- LSTM2 activations + cell ----------
      float h2l[4];
      #pragma unroll
      for (int j = 0; j < 4; ++j){
        const float ii = sgm(d0[j]);
        const float ff = sgm(d1[j]);
        const float gg = fmaf(2.f, sgm(d2[j]), -1.f);
        const float oo = sgm(d3[j]);
        c2[j] = fmaf(ff, c2[j], ii * gg);
        h2l[j] = oo * tnc(c2[j]);
      }
      pAu = pkrne(h2l[0], h2l[1]);
      pBu = pkrne(h2l[2], h2l[3]);

      // ---------- issue NEXT step's h2-recurrence MFMA ----------
      u32x4 bu; bu[0] = pAu; bu[1] = pBu; bu[2] = 0u; bu[3] = 0u;
      const f16x8 bv = __builtin_bit_cast(f16x8, bu);
      dp0 = __builtin_amdgcn_mfma_f32_16x16x32_f16(af[0], bv, cb[0], 0, 0, 0);
      dp1 = __builtin_amdgcn_mfma_f32_16x16x32_f16(af[1], bv, cb[1], 0, 0, 0);
      dp2 = __builtin_amdgcn_mfma_f32_16x16x32_f16(af[2], bv, cb[2], 0, 0, 0);
      dp3 = __builtin_amdgcn_mfma_f32_16x16x32_f16(af[3], bv, cb[3], 0, 0, 0);

      // ---------- LSTM3: lane-local ----------
      const f32x4 d3v = __builtin_amdgcn_mfma_f32_16x16x32_f16(a3f, bv, c3v, 0, 0, 0);
      const float p_i = fmaf(wh30, h3, d3v[0]);
      const float p_f = fmaf(wh31, h3, d3v[1]);
      const float p_g = fmaf(wh32, h3, d3v[2]);
      const float p_o = fmaf(wh33, h3, d3v[3]);
      const float i3 = sgm(p_i);
      const float f3 = sgm(p_f);
      const float g3 = fmaf(2.f, sgm(p_g), -1.f);
      const float q3 = sgm(p_o);
      c3 = fmaf(f3, c3, i3 * g3);
      h3 = q3 * tnc(c3);
      const float yv = fmaf(wl, h3, bl);

      if      (s == 0) o0 = cap ? yv : o0;
      else if (s == 1) o1 = cap ? yv : o1;
      else if (s == 2) o2 = cap ? yv : o2;
      else             o3 = cap ? yv : o3;
    }

    if ((ch & 3) == 3){
      float4 o4; o4.x = o0; o4.y = o1; o4.z = o2; o4.w = o3;
      *(float4*)(orow + (ch >> 2) * 16 + 4 * g) = o4;
    }
  }
  #undef LSTM1_STEP
}

extern "C" void kernel_launch(void* const* d_in, const int* in_sizes, int n_in,
                              void* d_out, int out_size, void* d_ws, size_t ws_size,
                              hipStream_t stream)
{
  const float* x     = (const float*)d_in[0];
  const float* w_ih1 = (const float*)d_in[1];
  const float* w_hh1 = (const float*)d_in[2];
  const float* b_ih1 = (const float*)d_in[3];
  const float* b_hh1 = (const float*)d_in[4];
  const float* w_ih2 = (const float*)d_in[5];
  const float* w_hh2 = (const float*)d_in[6];
  const float* b_ih2 = (const float*)d_in[7];
  const float* b_hh2 = (const float*)d_in[8];
  const float* w_ih3 = (const float*)d_in[9];
  const float* w_hh3 = (const float*)d_in[10];
  const float* b_ih3 = (const float*)d_in[11];
  const float* b_hh3 = (const float*)d_in[12];
  const float* w_lin = (const float*)d_in[13];
  const float* b_lin = (const float*)d_in[14];
  float* out = (float*)d_out;

  const int T = 2048;
  const int B = in_sizes[0] / (2 * T);     // 16384
  const int waves   = B / 16;              // 1024
  const int blocks  = waves / 4;           // 256

  lstm3_kernel<<<blocks, 256, 0, stream>>>(
      x, w_ih1, w_hh1, b_ih1, b_hh1,
      w_ih2, w_hh2, b_ih2, b_hh2,
      w_ih3, w_hh3, b_ih3, b_hh3,
      w_lin, b_lin, out, T);
}